// Round 1
// baseline (1008.348 us; speedup 1.0000x reference)
//
#include <hip/hip_runtime.h>

// GraphAttention: N=12288, IN=OUT=128.
// e_new = emb@W.T ; s = e_new@a1 ; t = e_new@a2
// e[i][j] = leaky(s_i + t_j) masked by adj; softmax rows; out = relu(att @ e_new)
//
// Plan:
//  k1: bf16 MFMA gemm emb@W.T -> Vt (bf16, transposed [d][j]), s[], t[] (fp32)
//  ktmax: Tmax = max_j t_j  (fixed softmax shift; no online softmax needed)
//  k2: streaming masked-softmax-PV. adj (604 MB) read once, coalesced int4.
//      P computed directly in MFMA A-layout; col-split x4, atomicAdd partials.
//  k3: out = relu(out / l)

#define NN 12288
#define DIM 128
#define CSPLIT 4
#define COLS_PER (NN / CSPLIT)  // 3072

typedef __bf16 bf16x8 __attribute__((ext_vector_type(8)));
typedef float f32x4 __attribute__((ext_vector_type(4)));

// ---------------- kernel 1: e_new = emb @ W.T (bf16 MFMA), emits Vt, s, t ----
__global__ __launch_bounds__(256) void k1_gemm(const float* __restrict__ emb,
                                               const float* __restrict__ W,
                                               const float* __restrict__ a,
                                               __bf16* __restrict__ Vt,
                                               float* __restrict__ s,
                                               float* __restrict__ t) {
  const int lane = threadIdx.x & 63;
  const int wave = threadIdx.x >> 6;
  const int m = lane & 15;
  const int quad = lane >> 4;
  const int row0 = blockIdx.x * 128 + wave * 32;  // this wave: rows row0..row0+31

  f32x4 acc[2][8];
#pragma unroll
  for (int mt = 0; mt < 2; mt++)
#pragma unroll
    for (int nb = 0; nb < 8; nb++) acc[mt][nb] = (f32x4){0.f, 0.f, 0.f, 0.f};

#pragma unroll
  for (int ks = 0; ks < 4; ks++) {
    const int k0 = ks * 32 + quad * 8;
    bf16x8 af[2];
#pragma unroll
    for (int mt = 0; mt < 2; mt++) {
      const float* ep = emb + (size_t)(row0 + mt * 16 + m) * DIM + k0;
      float4 lo = *(const float4*)ep;
      float4 hi = *(const float4*)(ep + 4);
      af[mt] = (bf16x8){(__bf16)lo.x, (__bf16)lo.y, (__bf16)lo.z, (__bf16)lo.w,
                        (__bf16)hi.x, (__bf16)hi.y, (__bf16)hi.z, (__bf16)hi.w};
    }
#pragma unroll
    for (int nb = 0; nb < 8; nb++) {
      const float* wp = W + (size_t)(nb * 16 + m) * DIM + k0;
      float4 lo = *(const float4*)wp;
      float4 hi = *(const float4*)(wp + 4);
      bf16x8 bf = {(__bf16)lo.x, (__bf16)lo.y, (__bf16)lo.z, (__bf16)lo.w,
                   (__bf16)hi.x, (__bf16)hi.y, (__bf16)hi.z, (__bf16)hi.w};
      acc[0][nb] = __builtin_amdgcn_mfma_f32_16x16x32_bf16(af[0], bf, acc[0][nb], 0, 0, 0);
      acc[1][nb] = __builtin_amdgcn_mfma_f32_16x16x32_bf16(af[1], bf, acc[1][nb], 0, 0, 0);
    }
  }

  float a1v[8], a2v[8];
#pragma unroll
  for (int nb = 0; nb < 8; nb++) {
    a1v[nb] = a[nb * 16 + m];
    a2v[nb] = a[DIM + nb * 16 + m];
  }
  // C/D layout: row = quad*4 + r, col = nb*16 + m
#pragma unroll
  for (int mt = 0; mt < 2; mt++) {
#pragma unroll
    for (int r = 0; r < 4; r++) {
      const int gr = row0 + mt * 16 + quad * 4 + r;
      float ps = 0.f, pt = 0.f;
#pragma unroll
      for (int nb = 0; nb < 8; nb++) {
        float e = acc[mt][nb][r];
        ps += e * a1v[nb];
        pt += e * a2v[nb];
        Vt[(size_t)(nb * 16 + m) * NN + gr] = (__bf16)e;
      }
      // reduce across the 16 m-lanes (same quad -> same row gr)
      ps += __shfl_xor(ps, 1); ps += __shfl_xor(ps, 2);
      ps += __shfl_xor(ps, 4); ps += __shfl_xor(ps, 8);
      pt += __shfl_xor(pt, 1); pt += __shfl_xor(pt, 2);
      pt += __shfl_xor(pt, 4); pt += __shfl_xor(pt, 8);
      if (m == 0) { s[gr] = ps; t[gr] = pt; }
    }
  }
}

// ---------------- kernel: Tmax = max(t) ------------------------------------
__global__ __launch_bounds__(256) void ktmax(const float* __restrict__ t,
                                             float* __restrict__ tmax) {
  __shared__ float red[256];
  float mx = -1e30f;
  for (int i = threadIdx.x; i < NN; i += 256) mx = fmaxf(mx, t[i]);
  red[threadIdx.x] = mx;
  __syncthreads();
  for (int off = 128; off; off >>= 1) {
    if ((int)threadIdx.x < off) red[threadIdx.x] = fmaxf(red[threadIdx.x], red[threadIdx.x + off]);
    __syncthreads();
  }
  if (threadIdx.x == 0) *tmax = red[0];
}

// ---------------- kernel 2: masked softmax + PV, streaming adj ---------------
__global__ __launch_bounds__(256) void k2_attn(const int* __restrict__ adj,
                                               const __bf16* __restrict__ Vt,
                                               const float* __restrict__ s,
                                               const float* __restrict__ t,
                                               const float* __restrict__ tmaxp,
                                               float* __restrict__ out,
                                               float* __restrict__ lws) {
  const int lane = threadIdx.x & 63;
  const int wave = threadIdx.x >> 6;
  const int m = lane & 15;
  const int quad = lane >> 4;
  const int row0 = blockIdx.x * 128 + wave * 32;
  const int col0 = blockIdx.y * COLS_PER;
  const int rowA = row0 + m;
  const int rowB = rowA + 16;

  const float Tmax = *tmaxp;
  const float sA = s[rowA], sB = s[rowB];
  const float uA = sA + Tmax, uB = sB + Tmax;
  const float mA = fmaxf(uA, 0.01f * uA);  // per-row fixed softmax shift (upper bound)
  const float mB = fmaxf(uB, 0.01f * uB);

  const int* adjA = adj + (size_t)rowA * NN + col0 + quad * 8;
  const int* adjB = adj + (size_t)rowB * NN + col0 + quad * 8;
  const float* tp = t + col0 + quad * 8;
  const __bf16* vp = Vt + (size_t)m * NN + col0 + quad * 8;

  f32x4 accA[8], accB[8];
#pragma unroll
  for (int nb = 0; nb < 8; nb++) {
    accA[nb] = (f32x4){0.f, 0.f, 0.f, 0.f};
    accB[nb] = (f32x4){0.f, 0.f, 0.f, 0.f};
  }
  float lA = 0.f, lB = 0.f;

  for (int kb = 0; kb < COLS_PER; kb += 32) {
    int4 aA0 = *(const int4*)(adjA + kb);
    int4 aA1 = *(const int4*)(adjA + kb + 4);
    int4 aB0 = *(const int4*)(adjB + kb);
    int4 aB1 = *(const int4*)(adjB + kb + 4);
    float4 t0 = *(const float4*)(tp + kb);
    float4 t1 = *(const float4*)(tp + kb + 4);
    bf16x8 bv[8];
#pragma unroll
    for (int nb = 0; nb < 8; nb++)
      bv[nb] = *(const bf16x8*)(vp + (size_t)nb * 16 * NN + kb);

    bf16x8 pA, pB;
#define PEL(frag, jj, tv, av, ss, mm, ll)                               \
    {                                                                   \
      float v = (ss) + (tv);                                            \
      float lv = fmaxf(v, 0.01f * v);                                   \
      float e = ((av) != 0) ? __expf(lv - (mm)) : 0.f;                  \
      (ll) += e;                                                        \
      frag[jj] = (__bf16)e;                                             \
    }
    PEL(pA, 0, t0.x, aA0.x, sA, mA, lA)
    PEL(pA, 1, t0.y, aA0.y, sA, mA, lA)
    PEL(pA, 2, t0.z, aA0.z, sA, mA, lA)
    PEL(pA, 3, t0.w, aA0.w, sA, mA, lA)
    PEL(pA, 4, t1.x, aA1.x, sA, mA, lA)
    PEL(pA, 5, t1.y, aA1.y, sA, mA, lA)
    PEL(pA, 6, t1.z, aA1.z, sA, mA, lA)
    PEL(pA, 7, t1.w, aA1.w, sA, mA, lA)
    PEL(pB, 0, t0.x, aB0.x, sB, mB, lB)
    PEL(pB, 1, t0.y, aB0.y, sB, mB, lB)
    PEL(pB, 2, t0.z, aB0.z, sB, mB, lB)
    PEL(pB, 3, t0.w, aB0.w, sB, mB, lB)
    PEL(pB, 4, t1.x, aB1.x, sB, mB, lB)
    PEL(pB, 5, t1.y, aB1.y, sB, mB, lB)
    PEL(pB, 6, t1.z, aB1.z, sB, mB, lB)
    PEL(pB, 7, t1.w, aB1.w, sB, mB, lB)
#undef PEL

#pragma unroll
    for (int nb = 0; nb < 8; nb++) {
      accA[nb] = __builtin_amdgcn_mfma_f32_16x16x32_bf16(pA, bv[nb], accA[nb], 0, 0, 0);
      accB[nb] = __builtin_amdgcn_mfma_f32_16x16x32_bf16(pB, bv[nb], accB[nb], 0, 0, 0);
    }
  }

  // row-sum partials: lanes {m, m+16, m+32, m+48} hold same row
  lA += __shfl_xor(lA, 16); lA += __shfl_xor(lA, 32);
  lB += __shfl_xor(lB, 16); lB += __shfl_xor(lB, 32);
  if (quad == 0) {
    atomicAdd(&lws[rowA], lA);
    atomicAdd(&lws[rowB], lB);
  }

  // C/D layout: row = quad*4 + r, col = nb*16 + m
#pragma unroll
  for (int nb = 0; nb < 8; nb++) {
#pragma unroll
    for (int r = 0; r < 4; r++) {
      atomicAdd(out + (size_t)(row0 + quad * 4 + r) * DIM + nb * 16 + m, accA[nb][r]);
      atomicAdd(out + (size_t)(row0 + 16 + quad * 4 + r) * DIM + nb * 16 + m, accB[nb][r]);
    }
  }
}

// ---------------- kernel 3: normalize + relu --------------------------------
__global__ __launch_bounds__(256) void k3_fin(float* __restrict__ out,
                                              const float* __restrict__ lws) {
  int idx = blockIdx.x * 256 + threadIdx.x;
  float l = lws[idx >> 7];
  float v = out[idx] / l;
  out[idx] = v > 0.f ? v : 0.f;
}

extern "C" void kernel_launch(void* const* d_in, const int* in_sizes, int n_in,
                              void* d_out, int out_size, void* d_ws, size_t ws_size,
                              hipStream_t stream) {
  (void)in_sizes; (void)n_in; (void)out_size; (void)ws_size;
  const float* emb = (const float*)d_in[0];
  const int* adj = (const int*)d_in[1];
  const float* W = (const float*)d_in[2];
  const float* a = (const float*)d_in[3];
  float* out = (float*)d_out;

  char* ws = (char*)d_ws;
  __bf16* Vt = (__bf16*)ws;                              // 128*12288*2 = 3,145,728 B
  float* s = (float*)(ws + 3145728);                     // 49,152 B
  float* t = (float*)(ws + 3145728 + 49152);             // 49,152 B
  float* lws = (float*)(ws + 3145728 + 2 * 49152);       // 49,152 B
  float* tmax = (float*)(ws + 3145728 + 3 * 49152);      // 4 B

  hipMemsetAsync(out, 0, (size_t)NN * DIM * 4, stream);
  hipMemsetAsync(lws, 0, (size_t)NN * 4, stream);

  k1_gemm<<<NN / 128, 256, 0, stream>>>(emb, W, a, Vt, s, t);
  ktmax<<<1, 256, 0, stream>>>(t, tmax);
  dim3 g2(NN / 128, CSPLIT);
  k2_attn<<<g2, 256, 0, stream>>>(adj, Vt, s, t, tmax, out, lws);
  k3_fin<<<NN * DIM / 256, 256, 0, stream>>>(out, lws);
}